// Round 1
// baseline (118.615 us; speedup 1.0000x reference)
//
#include <hip/hip_runtime.h>

// span(L,i)[b,d] = sum_{k=1..L} tensor[b, i+k, d] -> out[b, offL(L)+i, d],
// offL(L) = (L-1)*S - (L-1)*L/2. B=8, S=512, D=768 (192 float4), Lmax=8.
//
// R6: (1) quad-batch 4 starts per thread: i = {4u..4u+3}, u < 126.
//     11 loads (rows i+1..i+11) -> prefix P1..P11 -> 32 stores:
//       span(L, i+j) = P_{L+j} - P_j   (P_0 = 0), j = 0..3, L = 1..8
//     Cuts load instructions 3.5M -> 2.1M and halves thread count vs R5 pair.
// (2) nontemporal stores on all output: output is write-once / never re-read;
//     'nt' bypasses L2/L3 allocate so the 9-11x-reused input rows stay cached.
// R5 measured: K ~= 26.6 us vs ~17-18 us traffic roofline (99.8 MB writes +
// 12.6 MB reads). Prediction: K -> ~20-22 us.

typedef float f32x4v __attribute__((ext_vector_type(4)));

__device__ __forceinline__ float4 f4add(float4 a, float4 b) {
    return make_float4(a.x + b.x, a.y + b.y, a.z + b.z, a.w + b.w);
}
__device__ __forceinline__ float4 f4sub(float4 a, float4 b) {
    return make_float4(a.x - b.x, a.y - b.y, a.z - b.z, a.w - b.w);
}
__device__ __forceinline__ void st_nt(float4* p, float4 v) {
    union { float4 f; f32x4v v4; } u;
    u.f = v;
    __builtin_nontemporal_store(u.v4, reinterpret_cast<f32x4v*>(p));
}

__global__ __launch_bounds__(256) void span_quad_kernel(
    const float4* __restrict__ in,        // [B, S, D4]
    float4* __restrict__ out,             // [B, Ssum, D4]
    const int* __restrict__ maxspan_ptr)
{
    constexpr int S = 512, D4 = 192;
    constexpr int UQUAD = 126;            // u<126: quad (4u..4u+3), i<=503 full-span
    constexpr int UTOT  = 133;            // 126 quads + 7 tail singles (i=504..510)
    const int Lmax = *maxspan_ptr;        // wave-uniform

    const int tid = blockIdx.x * blockDim.x + threadIdx.x;
    const int total = 8 * UTOT * D4;      // 204,288 = 798 * 256 exactly
    if (tid >= total) return;

    const int d4   = tid % D4;
    const int rest = tid / D4;
    const int u    = rest % UTOT;
    const int b    = rest / UTOT;

    const int Ssum = Lmax * S - (Lmax * (Lmax + 1)) / 2;   // 4060 for Lmax=8

    const float4* inb  = in  + (size_t)b * S    * D4 + d4;
    float4*       outb = out + (size_t)b * Ssum * D4 + d4;

    if (Lmax == 8 && u < UQUAD) {
        const int i = 4 * u;                          // 0..500, step 4
        const float4* ip = inb + (size_t)(i + 1) * D4;
        // 11 independent loads: rows i+1 .. i+11 (max row 511 when i=500)
        float4 r0  = ip[0  * D4];
        float4 r1  = ip[1  * D4];
        float4 r2  = ip[2  * D4];
        float4 r3  = ip[3  * D4];
        float4 r4  = ip[4  * D4];
        float4 r5  = ip[5  * D4];
        float4 r6  = ip[6  * D4];
        float4 r7  = ip[7  * D4];
        float4 r8  = ip[8  * D4];
        float4 r9  = ip[9  * D4];
        float4 r10 = ip[10 * D4];
        // prefix sums P1..P11
        float4 p1  = r0;
        float4 p2  = f4add(p1,  r1);
        float4 p3  = f4add(p2,  r2);
        float4 p4  = f4add(p3,  r3);
        float4 p5  = f4add(p4,  r4);
        float4 p6  = f4add(p5,  r5);
        float4 p7  = f4add(p6,  r6);
        float4 p8  = f4add(p7,  r7);
        float4 p9  = f4add(p8,  r8);
        float4 p10 = f4add(p9,  r9);
        float4 p11 = f4add(p10, r10);
        // row offsets offL(L) = {0,511,1021,1530,2038,2545,3051,3556}
        float4* o = outb + (size_t)i * D4;
        // j=0: span(L, i) = P_L
        st_nt(&o[(0    + 0) * (size_t)D4], p1);
        st_nt(&o[(511  + 0) * (size_t)D4], p2);
        st_nt(&o[(1021 + 0) * (size_t)D4], p3);
        st_nt(&o[(1530 + 0) * (size_t)D4], p4);
        st_nt(&o[(2038 + 0) * (size_t)D4], p5);
        st_nt(&o[(2545 + 0) * (size_t)D4], p6);
        st_nt(&o[(3051 + 0) * (size_t)D4], p7);
        st_nt(&o[(3556 + 0) * (size_t)D4], p8);
        // j=1: span(L, i+1) = P_{L+1} - P_1
        st_nt(&o[(0    + 1) * (size_t)D4], f4sub(p2,  p1));
        st_nt(&o[(511  + 1) * (size_t)D4], f4sub(p3,  p1));
        st_nt(&o[(1021 + 1) * (size_t)D4], f4sub(p4,  p1));
        st_nt(&o[(1530 + 1) * (size_t)D4], f4sub(p5,  p1));
        st_nt(&o[(2038 + 1) * (size_t)D4], f4sub(p6,  p1));
        st_nt(&o[(2545 + 1) * (size_t)D4], f4sub(p7,  p1));
        st_nt(&o[(3051 + 1) * (size_t)D4], f4sub(p8,  p1));
        st_nt(&o[(3556 + 1) * (size_t)D4], f4sub(p9,  p1));
        // j=2: span(L, i+2) = P_{L+2} - P_2
        st_nt(&o[(0    + 2) * (size_t)D4], f4sub(p3,  p2));
        st_nt(&o[(511  + 2) * (size_t)D4], f4sub(p4,  p2));
        st_nt(&o[(1021 + 2) * (size_t)D4], f4sub(p5,  p2));
        st_nt(&o[(1530 + 2) * (size_t)D4], f4sub(p6,  p2));
        st_nt(&o[(2038 + 2) * (size_t)D4], f4sub(p7,  p2));
        st_nt(&o[(2545 + 2) * (size_t)D4], f4sub(p8,  p2));
        st_nt(&o[(3051 + 2) * (size_t)D4], f4sub(p9,  p2));
        st_nt(&o[(3556 + 2) * (size_t)D4], f4sub(p10, p2));
        // j=3: span(L, i+3) = P_{L+3} - P_3
        st_nt(&o[(0    + 3) * (size_t)D4], f4sub(p4,  p3));
        st_nt(&o[(511  + 3) * (size_t)D4], f4sub(p5,  p3));
        st_nt(&o[(1021 + 3) * (size_t)D4], f4sub(p6,  p3));
        st_nt(&o[(1530 + 3) * (size_t)D4], f4sub(p7,  p3));
        st_nt(&o[(2038 + 3) * (size_t)D4], f4sub(p8,  p3));
        st_nt(&o[(2545 + 3) * (size_t)D4], f4sub(p9,  p3));
        st_nt(&o[(3051 + 3) * (size_t)D4], f4sub(p10, p3));
        st_nt(&o[(3556 + 3) * (size_t)D4], f4sub(p11, p3));
    } else if (Lmax == 8) {
        // tail singles: i = 504..510, Lcap = 511-i in 1..7
        const int i = 504 + (u - UQUAD);
        const float4* ip = inb + (size_t)(i + 1) * D4;
        int Lcap = 511 - i;
        float4 acc = make_float4(0.f, 0.f, 0.f, 0.f);
        int offL = 0;
        for (int L = 1; L <= Lcap; ++L) {
            acc = f4add(acc, ip[(size_t)(L - 1) * D4]);
            st_nt(&outb[(size_t)(offL + i) * D4], acc);
            offL += S - L;
        }
    } else {
        // fully generic (Lmax != 8): handle this u's 1-4 start indices
        const int i_first = (u < UQUAD) ? 4 * u : 504 + (u - UQUAD);
        const int n_i     = (u < UQUAD) ? 4 : 1;
        for (int k = 0; k < n_i; ++k) {
            const int i = i_first + k;
            if (i >= S - 1) break;
            const float4* ip = inb + (size_t)(i + 1) * D4;
            int Lcap = S - 1 - i;
            if (Lcap > Lmax) Lcap = Lmax;
            float4 acc = make_float4(0.f, 0.f, 0.f, 0.f);
            int offL = 0;
            for (int L = 1; L <= Lcap; ++L) {
                acc = f4add(acc, ip[(size_t)(L - 1) * D4]);
                st_nt(&outb[(size_t)(offL + i) * D4], acc);
                offL += S - L;
            }
        }
    }
}

extern "C" void kernel_launch(void* const* d_in, const int* in_sizes, int n_in,
                              void* d_out, int out_size, void* d_ws, size_t ws_size,
                              hipStream_t stream) {
    const float* tensor = (const float*)d_in[0];
    const int* maxspan = (const int*)d_in[1];
    float* out = (float*)d_out;

    constexpr int D4 = 192, UTOT = 133;
    const int total = 8 * UTOT * D4;               // 204,288
    const int block = 256;
    const int grid = (total + block - 1) / block;  // 798

    span_quad_kernel<<<grid, block, 0, stream>>>(
        (const float4*)tensor, (float4*)out, maxspan);
}